// Round 18
// baseline (173.225 us; speedup 1.0000x reference)
//
#include <hip/hip_runtime.h>
#include <hip/hip_bf16.h>

typedef short bf16x8 __attribute__((ext_vector_type(8)));
typedef float f32x4 __attribute__((ext_vector_type(4)));
typedef unsigned short u16;
typedef unsigned char u8;
typedef unsigned int u32;

static constexpr int NN = 8192;   // nodes
static constexpr int NFE = 512;   // nfeat
static constexpr int NH = 128;    // nhid
static constexpr int NC = 40;     // nclass
static constexpr int NCP = 48;    // padded class cols (3 x 16)
static constexpr int KSPLIT = 8;

// ---------- helpers ----------
__device__ __forceinline__ u16 bf16bits(float v) {
  __hip_bfloat16 h = __float2bfloat16(v);
  return *(u16*)&h;
}

__device__ __forceinline__ void split_store(float s, u16* hi_p, u16* lo_p) {
  u16 h = bf16bits(s);
  float hf = __uint_as_float((unsigned)h << 16);
  *hi_p = h;
  *lo_p = bf16bits(s - hf);
}

__device__ __forceinline__ void split2(float a, float b, unsigned& hw, unsigned& lw) {
  u16 ha = bf16bits(a), hb = bf16bits(b);
  float ra = a - __uint_as_float((unsigned)ha << 16);
  float rb = b - __uint_as_float((unsigned)hb << 16);
  hw = (unsigned)ha | ((unsigned)hb << 16);
  lw = (unsigned)bf16bits(ra) | ((unsigned)bf16bits(rb) << 16);
}

// pack two small-int f32s (exact in bf16) into bf16x2 — single v_perm_b32
__device__ __forceinline__ unsigned pack_bf16(float a, float b) {
  return __builtin_amdgcn_perm(__float_as_uint(b), __float_as_uint(a), 0x07060302u);
}

// 8 u4 codes (one u32) -> bf16x8 (exact)
__device__ __forceinline__ bf16x8 cvtA8(u32 wv) {
  unsigned e = wv & 0x0F0F0F0Fu;         // codes 0,2,4,6
  unsigned o = (wv >> 4) & 0x0F0F0F0Fu;  // codes 1,3,5,7
  float e0 = (float)(e & 255u), e1 = (float)((e >> 8) & 255u);
  float e2 = (float)((e >> 16) & 255u), e3 = (float)(e >> 24);
  float o0 = (float)(o & 255u), o1 = (float)((o >> 8) & 255u);
  float o2 = (float)((o >> 16) & 255u), o3 = (float)(o >> 24);
  unsigned r4[4];
  r4[0] = pack_bf16(e0, o0);
  r4[1] = pack_bf16(e1, o1);
  r4[2] = pack_bf16(e2, o2);
  r4[3] = pack_bf16(e3, o3);
  return *(bf16x8*)r4;
}

// ---------- 1. fused front-end: role 0 (blocks 0..255)  = S1 = x@w1 (split MFMA,
//              w1 split in-kernel); role 1 (blocks 256..2303) = quantize adj -> u4.
__global__ __launch_bounds__(256, 4) void k_front(const float* __restrict__ x,
                                                  const float* __restrict__ w1,
                                                  const float* __restrict__ adj,
                                                  const float* __restrict__ alpha_p,
                                                  u32* __restrict__ codes32,
                                                  u16* __restrict__ s1h,
                                                  u16* __restrict__ s1l) {
  constexpr int BM = 32, BK = 64;
  __shared__ __align__(16) u16 sXh[BM * BK], sXl[BM * BK];   // 4 KB each
  __shared__ __align__(16) u16 sWh[NH * BK], sWl[NH * BK];   // 16 KB each
  const int tid = threadIdx.x;

  if (blockIdx.x >= 256) {
    // ---------------- quant role ----------------
    const float ia = 1.0f / alpha_p[0];
    size_t i = (size_t)(blockIdx.x - 256) * 256 + tid;      // u32 index (8 codes each)
    const size_t stride = (size_t)2048 * 256;
    for (int it = 0; it < 16; ++it, i += stride) {
      const float* src = adj + i * 8;
      float4 a = ((const float4*)src)[0];
      float4 b = ((const float4*)src)[1];
      u32 c0 = (u32)(int)rintf(fminf(a.x * ia, 1.0f) * 15.0f);
      u32 c1 = (u32)(int)rintf(fminf(a.y * ia, 1.0f) * 15.0f);
      u32 c2 = (u32)(int)rintf(fminf(a.z * ia, 1.0f) * 15.0f);
      u32 c3 = (u32)(int)rintf(fminf(a.w * ia, 1.0f) * 15.0f);
      u32 c4 = (u32)(int)rintf(fminf(b.x * ia, 1.0f) * 15.0f);
      u32 c5 = (u32)(int)rintf(fminf(b.y * ia, 1.0f) * 15.0f);
      u32 c6 = (u32)(int)rintf(fminf(b.z * ia, 1.0f) * 15.0f);
      u32 c7 = (u32)(int)rintf(fminf(b.w * ia, 1.0f) * 15.0f);
      codes32[i] = c0 | (c1 << 4) | (c2 << 8) | (c3 << 12) |
                   (c4 << 16) | (c5 << 20) | (c6 << 24) | (c7 << 28);
    }
    return;
  }

  // ---------------- xw1m role ----------------
  const int w = tid >> 6, l = tid & 63;
  const int r0 = blockIdx.x * BM;
  const int lr = l & 15, lg = l >> 4;
  const int xr = tid >> 3;      // 0..31
  const int xs8 = tid & 7;      // 16B slot
  const int wc_ = tid & 127;    // w1 column this thread stages
  const int wh_ = tid >> 7;     // k-half (groups 0-3 / 4-7)
  f32x4 acc[2][2];
#pragma unroll
  for (int m = 0; m < 2; ++m)
#pragma unroll
    for (int n = 0; n < 2; ++n) acc[m][n] = {0.f, 0.f, 0.f, 0.f};

  for (int k0 = 0; k0 < NFE; k0 += BK) {   // 8 steps
    // stage w1 tile: split f32 w1[k][c] -> sWh/sWl rows c, swizzled slots
#pragma unroll
    for (int gg = 0; gg < 4; ++gg) {
      int g = wh_ * 4 + gg;                // k-group (8 k values)
      float f[8];
#pragma unroll
      for (int j = 0; j < 8; ++j)
        f[j] = w1[(size_t)(k0 + g * 8 + j) * NH + wc_];
      unsigned hw[4], lw[4];
      split2(f[0], f[1], hw[0], lw[0]);
      split2(f[2], f[3], hw[1], lw[1]);
      split2(f[4], f[5], hw[2], lw[2]);
      split2(f[6], f[7], hw[3], lw[3]);
      int sl = g ^ (wc_ & 7);
      *(uint4*)((char*)sWh + wc_ * 128 + sl * 16) = *(uint4*)hw;
      *(uint4*)((char*)sWl + wc_ * 128 + sl * 16) = *(uint4*)lw;
    }
    // stage x tile (split in-register)
    const float* xp = x + (size_t)(r0 + xr) * NFE + k0 + xs8 * 8;
    float4 a = ((const float4*)xp)[0];
    float4 b = ((const float4*)xp)[1];
    unsigned hw[4], lw[4];
    split2(a.x, a.y, hw[0], lw[0]);
    split2(a.z, a.w, hw[1], lw[1]);
    split2(b.x, b.y, hw[2], lw[2]);
    split2(b.z, b.w, hw[3], lw[3]);
    int sl = xs8 ^ (xr & 7);
    *(uint4*)((char*)sXh + xr * 128 + sl * 16) = *(uint4*)hw;
    *(uint4*)((char*)sXl + xr * 128 + sl * 16) = *(uint4*)lw;
    __syncthreads();
#pragma unroll
    for (int s = 0; s < 2; ++s) {
      bf16x8 ah[2], al[2];
#pragma unroll
      for (int m = 0; m < 2; ++m) {
        int r = m * 16 + lr;
        int slot = (s * 4 + lg) ^ (r & 7);
        ah[m] = *(const bf16x8*)((const char*)sXh + r * 128 + slot * 16);
        al[m] = *(const bf16x8*)((const char*)sXl + r * 128 + slot * 16);
      }
#pragma unroll
      for (int n = 0; n < 2; ++n) {
        int c = w * 32 + n * 16 + lr;
        int slot = (s * 4 + lg) ^ (c & 7);
        bf16x8 bh = *(const bf16x8*)((const char*)sWh + c * 128 + slot * 16);
        bf16x8 bl = *(const bf16x8*)((const char*)sWl + c * 128 + slot * 16);
#pragma unroll
        for (int m = 0; m < 2; ++m) {
          acc[m][n] = __builtin_amdgcn_mfma_f32_16x16x32_bf16(ah[m], bh, acc[m][n], 0, 0, 0);
          acc[m][n] = __builtin_amdgcn_mfma_f32_16x16x32_bf16(ah[m], bl, acc[m][n], 0, 0, 0);
          acc[m][n] = __builtin_amdgcn_mfma_f32_16x16x32_bf16(al[m], bh, acc[m][n], 0, 0, 0);
        }
      }
    }
    __syncthreads();
  }
#pragma unroll
  for (int m = 0; m < 2; ++m)
#pragma unroll
    for (int n = 0; n < 2; ++n) {
      int c = w * 32 + n * 16 + lr;
      size_t base = (size_t)c * NN + r0 + m * 16 + lg * 4;
      ushort4 h4, l4;
      float v0 = acc[m][n][0], v1 = acc[m][n][1], v2 = acc[m][n][2], v3 = acc[m][n][3];
      h4.x = bf16bits(v0); l4.x = bf16bits(v0 - __uint_as_float((unsigned)h4.x << 16));
      h4.y = bf16bits(v1); l4.y = bf16bits(v1 - __uint_as_float((unsigned)h4.y << 16));
      h4.z = bf16bits(v2); l4.z = bf16bits(v2 - __uint_as_float((unsigned)h4.z << 16));
      h4.w = bf16bits(v3); l4.w = bf16bits(v3 - __uint_as_float((unsigned)h4.w << 16));
      *(ushort4*)(s1h + base) = h4;
      *(ushort4*)(s1l + base) = l4;
    }
}

// ---------- 2. gemmC: codes(u4) @ [S1_hi + S1_lo] — BM=128, SINGLE barrier/step ----------
// A fragment-direct from u4 codes into 2-deep ping-pong regs (no sA, no writeA,
// no second barrier). B double-buffered; issueB(kt+1) + loadA(kt+2) both issued
// BEFORE the 64-MFMA phase, so their latency rides under it.
__global__ __launch_bounds__(256, 2)
void k_gemmC(const u8* __restrict__ Ac,
             const u16* __restrict__ Bh,
             const u16* __restrict__ Bl,
             float* __restrict__ part) {
  constexpr int K = NN;
  constexpr int BM = 128, BN = 128;
  constexpr int NFN = 4;
  constexpr int KRANGE = K / KSPLIT;     // 1024
  constexpr int KSTEPS = KRANGE / 64;    // 16
  __shared__ __align__(16) u16 sBh[2][BN * 64];   // 2 x 16 KB
  __shared__ __align__(16) u16 sBl[2][BN * 64];   // 2 x 16 KB

  const int tid = threadIdx.x;
  const int w = tid >> 6, l = tid & 63;
  const int mtile = blockIdx.x >> 3;
  const int ks = blockIdx.x & 7;         // == XCD id -> codes/B slices L2-local
  const int m0 = mtile * BM;
  const int kbase = ks * KRANGE;
  const int wr = w >> 1, wc = w & 1;
  const int lr = l & 15, lg = l >> 4;

  f32x4 acc[4][NFN];
#pragma unroll
  for (int m = 0; m < 4; ++m)
#pragma unroll
    for (int n = 0; n < NFN; ++n) acc[m][n] = {0.f, 0.f, 0.f, 0.f};

  // A fragment base: row = m0 + wr*64 + m*16 + lr, byte col (k0>>1) + s*16 + lg*4
  const u8* aP = Ac + (size_t)(m0 + wr * 64 + lr) * (K / 2) + (kbase >> 1) + lg * 4;

  auto loadA = [&](int kt, u32 a[8]) {
#pragma unroll
    for (int m = 0; m < 4; ++m)
#pragma unroll
      for (int s = 0; s < 2; ++s)
        a[m * 2 + s] = *(const u32*)(aP + (size_t)m * 16 * (K / 2) + kt * 32 + s * 16);
  };
  auto issueB = [&](int kt, int buf) {
    const int k0 = kbase + kt * 64;
#pragma unroll
    for (int q = 0; q < 4; ++q) {
      int g = w * 4 + q;
      int r = g * 8 + (l >> 3);
      int sl = (l & 7) ^ (r & 7);
      __builtin_amdgcn_global_load_lds((const void*)(Bh + (size_t)r * K + k0 + sl * 8),
                                       (void*)(&sBh[buf][g * 512]), 16, 0, 0);
      __builtin_amdgcn_global_load_lds((const void*)(Bl + (size_t)r * K + k0 + sl * 8),
                                       (void*)(&sBl[buf][g * 512]), 16, 0, 0);
    }
  };
  auto mfmaPhase = [&](int buf, const u32 a[8]) {
#pragma unroll
    for (int s = 0; s < 2; ++s) {
      bf16x8 af[4];
#pragma unroll
      for (int m = 0; m < 4; ++m) af[m] = cvtA8(a[m * 2 + s]);
#pragma unroll
      for (int n = 0; n < NFN; ++n) {
        int c = wc * (NFN * 16) + n * 16 + lr;
        int slot = (s * 4 + lg) ^ (c & 7);
        bf16x8 bh = *(const bf16x8*)((const char*)&sBh[buf][0] + c * 128 + slot * 16);
        bf16x8 bl = *(const bf16x8*)((const char*)&sBl[buf][0] + c * 128 + slot * 16);
#pragma unroll
        for (int m = 0; m < 4; ++m) {
          acc[m][n] = __builtin_amdgcn_mfma_f32_16x16x32_bf16(af[m], bh, acc[m][n], 0, 0, 0);
          acc[m][n] = __builtin_amdgcn_mfma_f32_16x16x32_bf16(af[m], bl, acc[m][n], 0, 0, 0);
        }
      }
    }
  };

  // prologue: sB[0]=B(0); A(0),A(1) in regs
  u32 aA[8], aB[8], t0[8], t1[8];
  loadA(0, aA);
  issueB(0, 0);
  loadA(1, aB);
  __syncthreads();                       // one drain: B(0)+A(0)+A(1)

  for (int kt = 0; kt < KSTEPS; kt += 2) {
    // ---- even step kt (B buf 0, A regs aA) ----
    issueB(kt + 1, 1);                   // flies under MFMA
    const bool p0 = (kt + 2 < KSTEPS);
    if (p0) loadA(kt + 2, t0);           // flies under MFMA
    mfmaPhase(0, aA);
    if (p0) {
#pragma unroll
      for (int i = 0; i < 8; ++i) aA[i] = t0[i];
    }
    __syncthreads();                     // drains B(kt+1)+A(kt+2); frees sB[0]
    // ---- odd step kt+1 (B buf 1, A regs aB) ----
    if (kt + 2 < KSTEPS) issueB(kt + 2, 0);
    const bool p1 = (kt + 3 < KSTEPS);
    if (p1) loadA(kt + 3, t1);
    mfmaPhase(1, aB);
    if (p1) {
#pragma unroll
      for (int i = 0; i < 8; ++i) aB[i] = t1[i];
    }
    __syncthreads();
  }

  // epilogue: raw partial sums
#pragma unroll
  for (int m = 0; m < 4; ++m)
#pragma unroll
    for (int n = 0; n < NFN; ++n) {
      int cg = wc * (NFN * 16) + n * 16 + lr;
#pragma unroll
      for (int j = 0; j < 4; ++j) {
        int rg = m0 + wr * 64 + m * 16 + lg * 4 + j;
        part[((size_t)ks * NN + rg) * BN + cg] = acc[m][n][j];
      }
    }
}

// ---------- 4. gemmE: codes(u4) @ [S2_hi + S2_lo] — BM=128, BN=48, single barrier ----------
__global__ __launch_bounds__(256, 4)
void k_gemmE(const u8* __restrict__ Ac,
             const u16* __restrict__ Bh,
             const u16* __restrict__ Bl,
             float* __restrict__ part) {
  constexpr int K = NN;
  constexpr int BM = 128;
  constexpr int KRANGE = K / KSPLIT;     // 1024
  constexpr int KSTEPS = KRANGE / 64;    // 16
  __shared__ __align__(16) u16 sBh[2][NCP * 64];   // 2 x 6 KB
  __shared__ __align__(16) u16 sBl[2][NCP * 64];   // 2 x 6 KB

  const int tid = threadIdx.x;
  const int w = tid >> 6, l = tid & 63;
  const int mtile = blockIdx.x >> 3;
  const int ks = blockIdx.x & 7;
  const int m0 = mtile * BM;
  const int kbase = ks * KRANGE;
  const int lr = l & 15, lg = l >> 4;

  f32x4 acc[2][3];
#pragma unroll
  for (int m = 0; m < 2; ++m)
#pragma unroll
    for (int n = 0; n < 3; ++n) acc[m][n] = {0.f, 0.f, 0.f, 0.f};

  // A fragment base: row = m0 + w*32 + m*16 + lr
  const u8* aP = Ac + (size_t)(m0 + w * 32 + lr) * (K / 2) + (kbase >> 1) + lg * 4;

  auto loadA = [&](int kt, u32 a[4]) {
#pragma unroll
    for (int m = 0; m < 2; ++m)
#pragma unroll
      for (int s = 0; s < 2; ++s)
        a[m * 2 + s] = *(const u32*)(aP + (size_t)m * 16 * (K / 2) + kt * 32 + s * 16);
  };
  auto issueB = [&](int kt, int buf) {
    const int k0 = kbase + kt * 64;
    if (w < 3) {
#pragma unroll
      for (int q = 0; q < 2; ++q) {
        int i = w * 2 + q;                 // segment 0..5, rows i*8..i*8+7
        int r = i * 8 + (l >> 3);
        int sl = (l & 7) ^ (r & 7);
        __builtin_amdgcn_global_load_lds((const void*)(Bh + (size_t)r * K + k0 + sl * 8),
                                         (void*)(&sBh[buf][i * 512]), 16, 0, 0);
        __builtin_amdgcn_global_load_lds((const void*)(Bl + (size_t)r * K + k0 + sl * 8),
                                         (void*)(&sBl[buf][i * 512]), 16, 0, 0);
      }
    }
  };
  auto mfmaPhase = [&](int buf, const u32 a[4]) {
#pragma unroll
    for (int s = 0; s < 2; ++s) {
      bf16x8 af[2];
      af[0] = cvtA8(a[s]);
      af[1] = cvtA8(a[2 + s]);
#pragma unroll
      for (int n = 0; n < 3; ++n) {
        int c = n * 16 + lr;
        int slot = (s * 4 + lg) ^ (c & 7);
        bf16x8 bh = *(const bf16x8*)((const char*)&sBh[buf][0] + c * 128 + slot * 16);
        bf16x8 bl = *(const bf16x8*)((const char*)&sBl[buf][0] + c * 128 + slot * 16);
#pragma unroll
        for (int m = 0; m < 2; ++m) {
          acc[m][n] = __builtin_amdgcn_mfma_f32_16x16x32_bf16(af[m], bh, acc[m][n], 0, 0, 0);
          acc[m][n] = __builtin_amdgcn_mfma_f32_16x16x32_bf16(af[m], bl, acc[m][n], 0, 0, 0);
        }
      }
    }
  };

  // prologue
  u32 aA[4], aB[4], t0[4], t1[4];
  loadA(0, aA);
  issueB(0, 0);
  loadA(1, aB);
  __syncthreads();

  for (int kt = 0; kt < KSTEPS; kt += 2) {
    // ---- even step kt (B buf 0, A regs aA) ----
    issueB(kt + 1, 1);
    const bool p0 = (kt + 2 < KSTEPS);
    if (p0) loadA(kt + 2, t0);
    mfmaPhase(0, aA);
    if (p0) {
#pragma unroll
      for (int i = 0; i < 4; ++i) aA[i] = t0[i];
    }
    __syncthreads();
    // ---- odd step kt+1 (B buf 1, A regs aB) ----
    if (kt + 2 < KSTEPS) issueB(kt + 2, 0);
    const bool p1 = (kt + 3 < KSTEPS);
    if (p1) loadA(kt + 3, t1);
    mfmaPhase(1, aB);
    if (p1) {
#pragma unroll
      for (int i = 0; i < 4; ++i) aB[i] = t1[i];
    }
    __syncthreads();
  }

  // epilogue: raw partial sums [KSPLIT][NN][NCP]
#pragma unroll
  for (int m = 0; m < 2; ++m)
#pragma unroll
    for (int n = 0; n < 3; ++n) {
      int cg = n * 16 + lr;
#pragma unroll
      for (int j = 0; j < 4; ++j) {
        int rg = m0 + w * 32 + m * 16 + lg * 4 + j;
        part[((size_t)ks * NN + rg) * NCP + cg] = acc[m][n][j];
      }
    }
}

// ---------- 3. reduce partials -> h=relu(.) -> S2 = h@w2 (split, transposed, NCP cols) ----------
__global__ __launch_bounds__(256) void k_mid(const float* __restrict__ part1,
                                             const float* __restrict__ b1,
                                             const float* __restrict__ w2,
                                             const float* __restrict__ alpha_p,
                                             u16* __restrict__ s2h, u16* __restrict__ s2l) {
  __shared__ float hs[64][129];
  __shared__ float w2s[128][NC];
  const int t = threadIdx.x;
  const int r0 = blockIdx.x * 64;
  const float scale = alpha_p[0] * (1.0f / 15.0f);
  for (int i = t; i < 128 * NC; i += 256) w2s[i / NC][i % NC] = w2[i];
#pragma unroll
  for (int i = 0; i < 32; ++i) {
    int idx = t + i * 256;
    int r = idx >> 7, cc = idx & 127;
    float s = 0.f;
#pragma unroll
    for (int ksp = 0; ksp < KSPLIT; ++ksp)
      s += part1[((size_t)ksp * NN + r0 + r) * NH + cc];
    s = s * scale + b1[cc];
    hs[r][cc] = fmaxf(s, 0.f);
  }
  __syncthreads();
  for (int o = t; o < 64 * NC; o += 256) {
    int r = o / NC, n = o % NC;
    float a = 0.f;
    for (int cc = 0; cc < 128; ++cc) a = fmaf(hs[r][cc], w2s[cc][n], a);
    split_store(a, &s2h[(size_t)n * NN + r0 + r], &s2l[(size_t)n * NN + r0 + r]);
  }
  // zero-pad cols 40..47 (gemmE's BN=48 tile)
  for (int o = t; o < 64 * (NCP - NC); o += 256) {
    int n = NC + (o >> 6), r = o & 63;
    s2h[(size_t)n * NN + r0 + r] = 0;
    s2l[(size_t)n * NN + r0 + r] = 0;
  }
}

// ---------- 5. reduce partials + bias -> row softmax ----------
__global__ __launch_bounds__(256) void k_soft(const float* __restrict__ part2,
                                              const float* __restrict__ b2,
                                              const float* __restrict__ alpha_p,
                                              float* __restrict__ out) {
  const int w = threadIdx.x >> 6, l = threadIdx.x & 63;
  const int r = blockIdx.x * 4 + w;
  const float scale = alpha_p[0] * (1.0f / 15.0f);
  float v = -INFINITY;
  if (l < NC) {
    float s = 0.f;
#pragma unroll
    for (int ksp = 0; ksp < KSPLIT; ++ksp)
      s += part2[((size_t)ksp * NN + r) * NCP + l];
    v = s * scale + b2[l];
  }
  float m = v;
#pragma unroll
  for (int off = 32; off; off >>= 1) m = fmaxf(m, __shfl_xor(m, off, 64));
  float e = (l < NC) ? expf(v - m) : 0.f;
  float sum = e;
#pragma unroll
  for (int off = 32; off; off >>= 1) sum += __shfl_xor(sum, off, 64);
  if (l < NC) out[(size_t)r * NC + l] = e / sum;
}

extern "C" void kernel_launch(void* const* d_in, const int* in_sizes, int n_in,
                              void* d_out, int out_size, void* d_ws, size_t ws_size,
                              hipStream_t stream) {
  const float* x     = (const float*)d_in[0];
  const float* adj   = (const float*)d_in[1];
  const float* w1    = (const float*)d_in[2];
  const float* b1    = (const float*)d_in[3];
  const float* w2    = (const float*)d_in[4];
  const float* b2    = (const float*)d_in[5];
  const float* alpha = (const float*)d_in[6];
  float* out = (float*)d_out;

  char* ws = (char*)d_ws;
  u8* codes = (u8*)ws;                                   // u4-packed: 32 MB
  char* p = ws + (size_t)NN * NN / 2;
  u16* s1h = (u16*)p;           p += (size_t)NH * NN * 2;
  u16* s1l = (u16*)p;           p += (size_t)NH * NN * 2;
  u16* s2h = (u16*)p;           p += (size_t)NCP * NN * 2;
  u16* s2l = (u16*)p;           p += (size_t)NCP * NN * 2;
  float* part1 = (float*)p;     p += (size_t)KSPLIT * NN * NH * 4;    // 32 MB
  float* part2 = (float*)p;     p += (size_t)KSPLIT * NN * NCP * 4;   // 12.6 MB

  k_front<<<dim3(256 + 2048), dim3(256), 0, stream>>>(x, w1, adj, alpha,
                                                      (u32*)codes, s1h, s1l);
  k_gemmC<<<dim3((NN / 128) * KSPLIT), dim3(256), 0, stream>>>(codes, s1h, s1l, part1);
  k_mid<<<dim3(NN / 64), dim3(256), 0, stream>>>(part1, b1, w2, alpha, s2h, s2l);
  k_gemmE<<<dim3((NN / 128) * KSPLIT), dim3(256), 0, stream>>>(codes, s2h, s2l, part2);
  k_soft<<<dim3(NN / 4), dim3(256), 0, stream>>>(part2, b2, alpha, out);
}

// Round 19
// 155.754 us; speedup vs baseline: 1.1122x; 1.1122x over previous
//
#include <hip/hip_runtime.h>
#include <hip/hip_bf16.h>

typedef short bf16x8 __attribute__((ext_vector_type(8)));
typedef float f32x4 __attribute__((ext_vector_type(4)));
typedef unsigned short u16;
typedef unsigned char u8;
typedef unsigned int u32;

static constexpr int NN = 8192;   // nodes
static constexpr int NFE = 512;   // nfeat
static constexpr int NH = 128;    // nhid
static constexpr int NC = 40;     // nclass
static constexpr int NCP = 48;    // padded class cols (3 x 16)
static constexpr int KSPLIT = 8;

// ---------- helpers ----------
__device__ __forceinline__ u16 bf16bits(float v) {
  __hip_bfloat16 h = __float2bfloat16(v);
  return *(u16*)&h;
}

__device__ __forceinline__ void split_store(float s, u16* hi_p, u16* lo_p) {
  u16 h = bf16bits(s);
  float hf = __uint_as_float((unsigned)h << 16);
  *hi_p = h;
  *lo_p = bf16bits(s - hf);
}

__device__ __forceinline__ void split2(float a, float b, unsigned& hw, unsigned& lw) {
  u16 ha = bf16bits(a), hb = bf16bits(b);
  float ra = a - __uint_as_float((unsigned)ha << 16);
  float rb = b - __uint_as_float((unsigned)hb << 16);
  hw = (unsigned)ha | ((unsigned)hb << 16);
  lw = (unsigned)bf16bits(ra) | ((unsigned)bf16bits(rb) << 16);
}

// pack two small-int f32s (exact in bf16) into bf16x2 — single v_perm_b32
__device__ __forceinline__ unsigned pack_bf16(float a, float b) {
  return __builtin_amdgcn_perm(__float_as_uint(b), __float_as_uint(a), 0x07060302u);
}

// 8 u4 codes (one u32) -> bf16x8 (exact)
__device__ __forceinline__ bf16x8 cvtA8(u32 wv) {
  unsigned e = wv & 0x0F0F0F0Fu;         // codes 0,2,4,6
  unsigned o = (wv >> 4) & 0x0F0F0F0Fu;  // codes 1,3,5,7
  float e0 = (float)(e & 255u), e1 = (float)((e >> 8) & 255u);
  float e2 = (float)((e >> 16) & 255u), e3 = (float)(e >> 24);
  float o0 = (float)(o & 255u), o1 = (float)((o >> 8) & 255u);
  float o2 = (float)((o >> 16) & 255u), o3 = (float)(o >> 24);
  unsigned r4[4];
  r4[0] = pack_bf16(e0, o0);
  r4[1] = pack_bf16(e1, o1);
  r4[2] = pack_bf16(e2, o2);
  r4[3] = pack_bf16(e3, o3);
  return *(bf16x8*)r4;
}

// ---------- 1. fused front-end: role 0 (blocks 0..255)  = S1 = x@w1 (split MFMA,
//              w1 split in-kernel); role 1 (blocks 256..2303) = quantize adj -> u4.
__global__ __launch_bounds__(256, 4) void k_front(const float* __restrict__ x,
                                                  const float* __restrict__ w1,
                                                  const float* __restrict__ adj,
                                                  const float* __restrict__ alpha_p,
                                                  u32* __restrict__ codes32,
                                                  u16* __restrict__ s1h,
                                                  u16* __restrict__ s1l) {
  constexpr int BM = 32, BK = 64;
  __shared__ __align__(16) u16 sXh[BM * BK], sXl[BM * BK];   // 4 KB each
  __shared__ __align__(16) u16 sWh[NH * BK], sWl[NH * BK];   // 16 KB each
  const int tid = threadIdx.x;

  if (blockIdx.x >= 256) {
    // ---------------- quant role ----------------
    const float ia = 1.0f / alpha_p[0];
    size_t i = (size_t)(blockIdx.x - 256) * 256 + tid;      // u32 index (8 codes each)
    const size_t stride = (size_t)2048 * 256;
    for (int it = 0; it < 16; ++it, i += stride) {
      const float* src = adj + i * 8;
      float4 a = ((const float4*)src)[0];
      float4 b = ((const float4*)src)[1];
      u32 c0 = (u32)(int)rintf(fminf(a.x * ia, 1.0f) * 15.0f);
      u32 c1 = (u32)(int)rintf(fminf(a.y * ia, 1.0f) * 15.0f);
      u32 c2 = (u32)(int)rintf(fminf(a.z * ia, 1.0f) * 15.0f);
      u32 c3 = (u32)(int)rintf(fminf(a.w * ia, 1.0f) * 15.0f);
      u32 c4 = (u32)(int)rintf(fminf(b.x * ia, 1.0f) * 15.0f);
      u32 c5 = (u32)(int)rintf(fminf(b.y * ia, 1.0f) * 15.0f);
      u32 c6 = (u32)(int)rintf(fminf(b.z * ia, 1.0f) * 15.0f);
      u32 c7 = (u32)(int)rintf(fminf(b.w * ia, 1.0f) * 15.0f);
      codes32[i] = c0 | (c1 << 4) | (c2 << 8) | (c3 << 12) |
                   (c4 << 16) | (c5 << 20) | (c6 << 24) | (c7 << 28);
    }
    return;
  }

  // ---------------- xw1m role ----------------
  const int w = tid >> 6, l = tid & 63;
  const int r0 = blockIdx.x * BM;
  const int lr = l & 15, lg = l >> 4;
  const int xr = tid >> 3;      // 0..31
  const int xs8 = tid & 7;      // 16B slot
  const int wc_ = tid & 127;    // w1 column this thread stages
  const int wh_ = tid >> 7;     // k-half (groups 0-3 / 4-7)
  f32x4 acc[2][2];
#pragma unroll
  for (int m = 0; m < 2; ++m)
#pragma unroll
    for (int n = 0; n < 2; ++n) acc[m][n] = {0.f, 0.f, 0.f, 0.f};

  for (int k0 = 0; k0 < NFE; k0 += BK) {   // 8 steps
    // stage w1 tile: split f32 w1[k][c] -> sWh/sWl rows c, swizzled slots
#pragma unroll
    for (int gg = 0; gg < 4; ++gg) {
      int g = wh_ * 4 + gg;                // k-group (8 k values)
      float f[8];
#pragma unroll
      for (int j = 0; j < 8; ++j)
        f[j] = w1[(size_t)(k0 + g * 8 + j) * NH + wc_];
      unsigned hw[4], lw[4];
      split2(f[0], f[1], hw[0], lw[0]);
      split2(f[2], f[3], hw[1], lw[1]);
      split2(f[4], f[5], hw[2], lw[2]);
      split2(f[6], f[7], hw[3], lw[3]);
      int sl = g ^ (wc_ & 7);
      *(uint4*)((char*)sWh + wc_ * 128 + sl * 16) = *(uint4*)hw;
      *(uint4*)((char*)sWl + wc_ * 128 + sl * 16) = *(uint4*)lw;
    }
    // stage x tile (split in-register)
    const float* xp = x + (size_t)(r0 + xr) * NFE + k0 + xs8 * 8;
    float4 a = ((const float4*)xp)[0];
    float4 b = ((const float4*)xp)[1];
    unsigned hw[4], lw[4];
    split2(a.x, a.y, hw[0], lw[0]);
    split2(a.z, a.w, hw[1], lw[1]);
    split2(b.x, b.y, hw[2], lw[2]);
    split2(b.z, b.w, hw[3], lw[3]);
    int sl = xs8 ^ (xr & 7);
    *(uint4*)((char*)sXh + xr * 128 + sl * 16) = *(uint4*)hw;
    *(uint4*)((char*)sXl + xr * 128 + sl * 16) = *(uint4*)lw;
    __syncthreads();
#pragma unroll
    for (int s = 0; s < 2; ++s) {
      bf16x8 ah[2], al[2];
#pragma unroll
      for (int m = 0; m < 2; ++m) {
        int r = m * 16 + lr;
        int slot = (s * 4 + lg) ^ (r & 7);
        ah[m] = *(const bf16x8*)((const char*)sXh + r * 128 + slot * 16);
        al[m] = *(const bf16x8*)((const char*)sXl + r * 128 + slot * 16);
      }
#pragma unroll
      for (int n = 0; n < 2; ++n) {
        int c = w * 32 + n * 16 + lr;
        int slot = (s * 4 + lg) ^ (c & 7);
        bf16x8 bh = *(const bf16x8*)((const char*)sWh + c * 128 + slot * 16);
        bf16x8 bl = *(const bf16x8*)((const char*)sWl + c * 128 + slot * 16);
#pragma unroll
        for (int m = 0; m < 2; ++m) {
          acc[m][n] = __builtin_amdgcn_mfma_f32_16x16x32_bf16(ah[m], bh, acc[m][n], 0, 0, 0);
          acc[m][n] = __builtin_amdgcn_mfma_f32_16x16x32_bf16(ah[m], bl, acc[m][n], 0, 0, 0);
          acc[m][n] = __builtin_amdgcn_mfma_f32_16x16x32_bf16(al[m], bh, acc[m][n], 0, 0, 0);
        }
      }
    }
    __syncthreads();
  }
#pragma unroll
  for (int m = 0; m < 2; ++m)
#pragma unroll
    for (int n = 0; n < 2; ++n) {
      int c = w * 32 + n * 16 + lr;
      size_t base = (size_t)c * NN + r0 + m * 16 + lg * 4;
      ushort4 h4, l4;
      float v0 = acc[m][n][0], v1 = acc[m][n][1], v2 = acc[m][n][2], v3 = acc[m][n][3];
      h4.x = bf16bits(v0); l4.x = bf16bits(v0 - __uint_as_float((unsigned)h4.x << 16));
      h4.y = bf16bits(v1); l4.y = bf16bits(v1 - __uint_as_float((unsigned)h4.y << 16));
      h4.z = bf16bits(v2); l4.z = bf16bits(v2 - __uint_as_float((unsigned)h4.z << 16));
      h4.w = bf16bits(v3); l4.w = bf16bits(v3 - __uint_as_float((unsigned)h4.w << 16));
      *(ushort4*)(s1h + base) = h4;
      *(ushort4*)(s1l + base) = l4;
    }
}

// ---------- 2. gemmC: codes(u4) @ [S1_hi + S1_lo] — BM=128, r13 schedule,
//              A prefetch moved to loop-top (ping-pong regs) ----------
__global__ __launch_bounds__(256, 3)
void k_gemmC(const u8* __restrict__ Ac,
             const u16* __restrict__ Bh,
             const u16* __restrict__ Bl,
             float* __restrict__ part) {
  constexpr int K = NN;
  constexpr int BM = 128, BN = 128;
  constexpr int NFN = 4;
  constexpr int KRANGE = K / KSPLIT;     // 1024
  constexpr int KSTEPS = KRANGE / 64;    // 16
  __shared__ __align__(16) u16 sA[BM * 64];       // 16 KB
  __shared__ __align__(16) u16 sBh[BN * 64];      // 16 KB
  __shared__ __align__(16) u16 sBl[BN * 64];      // 16 KB

  const int tid = threadIdx.x;
  const int w = tid >> 6, l = tid & 63;
  const int mtile = blockIdx.x >> 3;
  const int ks = blockIdx.x & 7;         // == XCD id -> codes/B slices L2-local
  const int m0 = mtile * BM;
  const int kbase = ks * KRANGE;
  const int wr = w >> 1, wc = w & 1;
  const int lr = l & 15, lg = l >> 4;
  const int ar = tid >> 1;               // A row 0..127
  const int ah = tid & 1;                // 32-code (16B) half

  f32x4 acc[4][NFN];
#pragma unroll
  for (int m = 0; m < 4; ++m)
#pragma unroll
    for (int n = 0; n < NFN; ++n) acc[m][n] = {0.f, 0.f, 0.f, 0.f};

  auto loadA = [&](int kt) -> uint4 {
    const int k0 = kbase + kt * 64;
    return *(const uint4*)(Ac + (size_t)(m0 + ar) * (K / 2) + (k0 >> 1) + ah * 16);
  };
  auto issueB = [&](int kt) {
    const int k0 = kbase + kt * 64;
#pragma unroll
    for (int q = 0; q < 4; ++q) {
      int g = w * 4 + q;
      int r = g * 8 + (l >> 3);
      int sl = (l & 7) ^ (r & 7);
      __builtin_amdgcn_global_load_lds((const void*)(Bh + (size_t)r * K + k0 + sl * 8),
                                       (void*)(sBh + g * 512), 16, 0, 0);
      __builtin_amdgcn_global_load_lds((const void*)(Bl + (size_t)r * K + k0 + sl * 8),
                                       (void*)(sBl + g * 512), 16, 0, 0);
    }
  };
  auto writeA = [&](uint4 pA) {
    u32 pw[4] = {pA.x, pA.y, pA.z, pA.w};
#pragma unroll
    for (int j = 0; j < 4; ++j) {
      bf16x8 v = cvtA8(pw[j]);
      int s = ah * 4 + j;
      int sl = s ^ (ar & 7);
      *(uint4*)((char*)sA + ar * 128 + sl * 16) = *(uint4*)&v;
    }
  };

  // prologue: stage step 0; prefetch A(1)
  uint4 pAc = loadA(0);
  issueB(0);
  writeA(pAc);
  pAc = loadA(1);                        // A(kt+1) for the first iteration
  __syncthreads();

  for (int kt = 0; kt < KSTEPS; ++kt) {
    uint4 pAn;
    const bool haveN = (kt + 2 < KSTEPS);
    if (haveN) pAn = loadA(kt + 2);      // issued at loop-top: flies over MFMA
#pragma unroll
    for (int s = 0; s < 2; ++s) {
      bf16x8 af[4];
#pragma unroll
      for (int m = 0; m < 4; ++m) {
        int r = wr * 64 + m * 16 + lr;
        int slot = (s * 4 + lg) ^ (r & 7);
        af[m] = *(const bf16x8*)((const char*)sA + r * 128 + slot * 16);
      }
#pragma unroll
      for (int n = 0; n < NFN; ++n) {
        int c = wc * (NFN * 16) + n * 16 + lr;
        int slot = (s * 4 + lg) ^ (c & 7);
        bf16x8 bh = *(const bf16x8*)((const char*)sBh + c * 128 + slot * 16);
        bf16x8 bl = *(const bf16x8*)((const char*)sBl + c * 128 + slot * 16);
#pragma unroll
        for (int m = 0; m < 4; ++m) {
          acc[m][n] = __builtin_amdgcn_mfma_f32_16x16x32_bf16(af[m], bh, acc[m][n], 0, 0, 0);
          acc[m][n] = __builtin_amdgcn_mfma_f32_16x16x32_bf16(af[m], bl, acc[m][n], 0, 0, 0);
        }
      }
    }
    __syncthreads();            // all waves done reading sA/sB
    if (kt + 1 < KSTEPS) {
      issueB(kt + 1);           // restage; latency amortized across resident blocks
      writeA(pAc);              // A(kt+1), loaded a full step ago
      if (haveN) pAc = pAn;
    }
    __syncthreads();            // drain: B-DMAs only (A prefetch long complete)
  }

  // epilogue: raw partial sums
#pragma unroll
  for (int m = 0; m < 4; ++m)
#pragma unroll
    for (int n = 0; n < NFN; ++n) {
      int cg = wc * (NFN * 16) + n * 16 + lr;
#pragma unroll
      for (int j = 0; j < 4; ++j) {
        int rg = m0 + wr * 64 + m * 16 + lg * 4 + j;
        part[((size_t)ks * NN + rg) * BN + cg] = acc[m][n][j];
      }
    }
}

// ---------- 4. gemmE: codes(u4) @ [S2_hi + S2_lo] — BM=128, BN=48, same reorder ----------
__global__ __launch_bounds__(256, 4)
void k_gemmE(const u8* __restrict__ Ac,
             const u16* __restrict__ Bh,
             const u16* __restrict__ Bl,
             float* __restrict__ part) {
  constexpr int K = NN;
  constexpr int BM = 128;
  constexpr int KRANGE = K / KSPLIT;     // 1024
  constexpr int KSTEPS = KRANGE / 64;    // 16
  __shared__ __align__(16) u16 sA[BM * 64];       // 16 KB
  __shared__ __align__(16) u16 sBh[NCP * 64];     // 6 KB
  __shared__ __align__(16) u16 sBl[NCP * 64];     // 6 KB

  const int tid = threadIdx.x;
  const int w = tid >> 6, l = tid & 63;
  const int mtile = blockIdx.x >> 3;
  const int ks = blockIdx.x & 7;
  const int m0 = mtile * BM;
  const int kbase = ks * KRANGE;
  const int lr = l & 15, lg = l >> 4;
  const int ar = tid >> 1;               // A row 0..127
  const int ah = tid & 1;                // 32-code (16B) half

  f32x4 acc[2][3];
#pragma unroll
  for (int m = 0; m < 2; ++m)
#pragma unroll
    for (int n = 0; n < 3; ++n) acc[m][n] = {0.f, 0.f, 0.f, 0.f};

  auto loadA = [&](int kt) -> uint4 {
    const int k0 = kbase + kt * 64;
    return *(const uint4*)(Ac + (size_t)(m0 + ar) * (K / 2) + (k0 >> 1) + ah * 16);
  };
  auto issueB = [&](int kt) {
    const int k0 = kbase + kt * 64;
    if (w < 3) {
#pragma unroll
      for (int q = 0; q < 2; ++q) {
        int i = w * 2 + q;                 // segment 0..5, covers rows i*8..i*8+7
        int r = i * 8 + (l >> 3);
        int sl = (l & 7) ^ (r & 7);
        __builtin_amdgcn_global_load_lds((const void*)(Bh + (size_t)r * K + k0 + sl * 8),
                                         (void*)(sBh + i * 512), 16, 0, 0);
        __builtin_amdgcn_global_load_lds((const void*)(Bl + (size_t)r * K + k0 + sl * 8),
                                         (void*)(sBl + i * 512), 16, 0, 0);
      }
    }
  };
  auto writeA = [&](uint4 pA) {
    u32 pw[4] = {pA.x, pA.y, pA.z, pA.w};
#pragma unroll
    for (int j = 0; j < 4; ++j) {
      bf16x8 v = cvtA8(pw[j]);
      int s = ah * 4 + j;
      int sl = s ^ (ar & 7);
      *(uint4*)((char*)sA + ar * 128 + sl * 16) = *(uint4*)&v;
    }
  };

  // prologue
  uint4 pAc = loadA(0);
  issueB(0);
  writeA(pAc);
  pAc = loadA(1);
  __syncthreads();

  for (int kt = 0; kt < KSTEPS; ++kt) {
    uint4 pAn;
    const bool haveN = (kt + 2 < KSTEPS);
    if (haveN) pAn = loadA(kt + 2);      // loop-top prefetch
#pragma unroll
    for (int s = 0; s < 2; ++s) {
      bf16x8 af[2];
#pragma unroll
      for (int m = 0; m < 2; ++m) {
        int r = w * 32 + m * 16 + lr;
        int slot = (s * 4 + lg) ^ (r & 7);
        af[m] = *(const bf16x8*)((const char*)sA + r * 128 + slot * 16);
      }
#pragma unroll
      for (int n = 0; n < 3; ++n) {
        int c = n * 16 + lr;
        int slot = (s * 4 + lg) ^ (c & 7);
        bf16x8 bh = *(const bf16x8*)((const char*)sBh + c * 128 + slot * 16);
        bf16x8 bl = *(const bf16x8*)((const char*)sBl + c * 128 + slot * 16);
#pragma unroll
        for (int m = 0; m < 2; ++m) {
          acc[m][n] = __builtin_amdgcn_mfma_f32_16x16x32_bf16(af[m], bh, acc[m][n], 0, 0, 0);
          acc[m][n] = __builtin_amdgcn_mfma_f32_16x16x32_bf16(af[m], bl, acc[m][n], 0, 0, 0);
        }
      }
    }
    __syncthreads();
    if (kt + 1 < KSTEPS) {
      issueB(kt + 1);
      writeA(pAc);
      if (haveN) pAc = pAn;
    }
    __syncthreads();
  }

  // epilogue: raw partial sums [KSPLIT][NN][NCP]
#pragma unroll
  for (int m = 0; m < 2; ++m)
#pragma unroll
    for (int n = 0; n < 3; ++n) {
      int cg = n * 16 + lr;
#pragma unroll
      for (int j = 0; j < 4; ++j) {
        int rg = m0 + w * 32 + m * 16 + lg * 4 + j;
        part[((size_t)ks * NN + rg) * NCP + cg] = acc[m][n][j];
      }
    }
}

// ---------- 3. reduce partials -> h=relu(.) -> S2 = h@w2 (split, transposed, NCP cols) ----------
__global__ __launch_bounds__(256) void k_mid(const float* __restrict__ part1,
                                             const float* __restrict__ b1,
                                             const float* __restrict__ w2,
                                             const float* __restrict__ alpha_p,
                                             u16* __restrict__ s2h, u16* __restrict__ s2l) {
  __shared__ float hs[64][129];
  __shared__ float w2s[128][NC];
  const int t = threadIdx.x;
  const int r0 = blockIdx.x * 64;
  const float scale = alpha_p[0] * (1.0f / 15.0f);
  for (int i = t; i < 128 * NC; i += 256) w2s[i / NC][i % NC] = w2[i];
#pragma unroll
  for (int i = 0; i < 32; ++i) {
    int idx = t + i * 256;
    int r = idx >> 7, cc = idx & 127;
    float s = 0.f;
#pragma unroll
    for (int ksp = 0; ksp < KSPLIT; ++ksp)
      s += part1[((size_t)ksp * NN + r0 + r) * NH + cc];
    s = s * scale + b1[cc];
    hs[r][cc] = fmaxf(s, 0.f);
  }
  __syncthreads();
  for (int o = t; o < 64 * NC; o += 256) {
    int r = o / NC, n = o % NC;
    float a = 0.f;
    for (int cc = 0; cc < 128; ++cc) a = fmaf(hs[r][cc], w2s[cc][n], a);
    split_store(a, &s2h[(size_t)n * NN + r0 + r], &s2l[(size_t)n * NN + r0 + r]);
  }
  // zero-pad cols 40..47 (gemmE's BN=48 tile)
  for (int o = t; o < 64 * (NCP - NC); o += 256) {
    int n = NC + (o >> 6), r = o & 63;
    s2h[(size_t)n * NN + r0 + r] = 0;
    s2l[(size_t)n * NN + r0 + r] = 0;
  }
}

// ---------- 5. reduce partials + bias -> row softmax ----------
__global__ __launch_bounds__(256) void k_soft(const float* __restrict__ part2,
                                              const float* __restrict__ b2,
                                              const float* __restrict__ alpha_p,
                                              float* __restrict__ out) {
  const int w = threadIdx.x >> 6, l = threadIdx.x & 63;
  const int r = blockIdx.x * 4 + w;
  const float scale = alpha_p[0] * (1.0f / 15.0f);
  float v = -INFINITY;
  if (l < NC) {
    float s = 0.f;
#pragma unroll
    for (int ksp = 0; ksp < KSPLIT; ++ksp)
      s += part2[((size_t)ksp * NN + r) * NCP + l];
    v = s * scale + b2[l];
  }
  float m = v;
#pragma unroll
  for (int off = 32; off; off >>= 1) m = fmaxf(m, __shfl_xor(m, off, 64));
  float e = (l < NC) ? expf(v - m) : 0.f;
  float sum = e;
#pragma unroll
  for (int off = 32; off; off >>= 1) sum += __shfl_xor(sum, off, 64);
  if (l < NC) out[(size_t)r * NC + l] = e / sum;
}

extern "C" void kernel_launch(void* const* d_in, const int* in_sizes, int n_in,
                              void* d_out, int out_size, void* d_ws, size_t ws_size,
                              hipStream_t stream) {
  const float* x     = (const float*)d_in[0];
  const float* adj   = (const float*)d_in[1];
  const float* w1    = (const float*)d_in[2];
  const float* b1    = (const float*)d_in[3];
  const float* w2    = (const float*)d_in[4];
  const float* b2    = (const float*)d_in[5];
  const float* alpha = (const float*)d_in[6];
  float* out = (float*)d_out;

  char* ws = (char*)d_ws;
  u8* codes = (u8*)ws;                                   // u4-packed: 32 MB
  char* p = ws + (size_t)NN * NN / 2;
  u16* s1h = (u16*)p;           p += (size_t)NH * NN * 2;
  u16* s1l = (u16*)p;           p += (size_t)NH * NN * 2;
  u16* s2h = (u16*)p;           p += (size_t)NCP * NN * 2;
  u16* s2l = (u16*)p;           p += (size_t)NCP * NN * 2;
  float* part1 = (float*)p;     p += (size_t)KSPLIT * NN * NH * 4;    // 32 MB
  float* part2 = (float*)p;     p += (size_t)KSPLIT * NN * NCP * 4;   // 12.6 MB

  k_front<<<dim3(256 + 2048), dim3(256), 0, stream>>>(x, w1, adj, alpha,
                                                      (u32*)codes, s1h, s1l);
  k_gemmC<<<dim3((NN / 128) * KSPLIT), dim3(256), 0, stream>>>(codes, s1h, s1l, part1);
  k_mid<<<dim3(NN / 64), dim3(256), 0, stream>>>(part1, b1, w2, alpha, s2h, s2l);
  k_gemmE<<<dim3((NN / 128) * KSPLIT), dim3(256), 0, stream>>>(codes, s2h, s2l, part2);
  k_soft<<<dim3(NN / 4), dim3(256), 0, stream>>>(part2, b2, alpha, out);
}